// Round 3
// baseline (537.974 us; speedup 1.0000x reference)
//
#include <hip/hip_runtime.h>
#include <stdint.h>

#define BATCH 32768
#define NN    2500
#define NPAD  2560
#define DIM   256

#define BM 128
#define BN 128

typedef __attribute__((ext_vector_type(8))) short short8;
typedef __attribute__((ext_vector_type(4))) float float4_;

__device__ __forceinline__ unsigned short f2bf(float f) {
  union { float f; uint32_t u; } v; v.f = f;
  uint32_t u = v.u;
  return (unsigned short)((u + 0x7FFFu + ((u >> 16) & 1u)) >> 16);
}

// ---------------- prep: fp32 -> bf16 copy + exact fp32 row norm ----------------
// one wave per row; rows >= nvalid are zero-filled (for W padding to NPAD)
__global__ void prep_rows(const float* __restrict__ in, unsigned short* __restrict__ outb,
                          float* __restrict__ sq, int nrows, int nvalid) {
  int row  = blockIdx.x * 4 + (threadIdx.x >> 6);
  int lane = threadIdx.x & 63;
  if (row >= nrows) return;
  float4 v = make_float4(0.f, 0.f, 0.f, 0.f);
  if (row < nvalid) v = ((const float4*)(in + (size_t)row * DIM))[lane];
  float s = v.x * v.x + v.y * v.y + v.z * v.z + v.w * v.w;
  *(ushort4*)(outb + (size_t)row * DIM + lane * 4) =
      make_ushort4(f2bf(v.x), f2bf(v.y), f2bf(v.z), f2bf(v.w));
  for (int off = 32; off > 0; off >>= 1) s += __shfl_down(s, off, 64);
  if (lane == 0) sq[row] = s;
}

// ---------------- main GEMM: no LDS, no barriers ----------------
// K=256 is tiny; X-bf16 (16.8 MB) is LLC-resident, W-bf16 (1.28 MB) fits every
// XCD L2. Fragments are loaded straight from global as dwordx4 with a depth-1
// register pipeline (load half-chunk hk+1 while issuing MFMAs of hk), so vmcnt
// never drains and waves desync freely -> compute overlaps other blocks' stores.
__global__ __launch_bounds__(256, 3)
void cdist_gemm_direct(const unsigned short* __restrict__ Xb,
                       const unsigned short* __restrict__ Wb,
                       const float* __restrict__ xsq, const float* __restrict__ wsq,
                       float* __restrict__ out) {
  const int tid  = threadIdx.x;
  const int lane = tid & 63;
  const int wave = tid >> 6;
  const int m0   = blockIdx.x * BM;
  const int n0   = blockIdx.y * BN;
  const int wr   = wave >> 1;       // wave row (0..1): 64 M-rows
  const int wc   = wave & 1;        // wave col (0..1): 64 N-cols
  const int q    = lane >> 4;       // quad 0..3 -> K-subgroup q*8
  const int i    = lane & 15;       // row-within-16

  // A-operand layout for mfma_f32_16x16x32_bf16: A[m=lane&15][k=(lane>>4)*8+j]
  const unsigned short* pA = Xb + (size_t)(m0 + wr * 64 + i) * DIM + q * 8;
  const unsigned short* pB = Wb + (size_t)(n0 + wc * 64 + i) * DIM + q * 8;

  float4_ acc[4][4] = {};
  short8 a[2][4], b[2][4];

  // preload half-chunk 0 (K elems 0..31)
#pragma unroll
  for (int t = 0; t < 4; ++t) {
    a[0][t] = *(const short8*)(pA + (size_t)(t * 16) * DIM);
    b[0][t] = *(const short8*)(pB + (size_t)(t * 16) * DIM);
  }

#pragma unroll
  for (int hk = 0; hk < 8; ++hk) {   // 8 half-chunks of K=32
    const int cur = hk & 1, nxt = cur ^ 1;
    if (hk < 7) {
#pragma unroll
      for (int t = 0; t < 4; ++t) {
        a[nxt][t] = *(const short8*)(pA + (size_t)(t * 16) * DIM + (hk + 1) * 32);
        b[nxt][t] = *(const short8*)(pB + (size_t)(t * 16) * DIM + (hk + 1) * 32);
      }
    }
#pragma unroll
    for (int ti = 0; ti < 4; ++ti)
#pragma unroll
      for (int tj = 0; tj < 4; ++tj)
        acc[ti][tj] = __builtin_amdgcn_mfma_f32_16x16x32_bf16(
            a[cur][ti], b[cur][tj], acc[ti][tj], 0, 0, 0);
  }

  // epilogue: d = sqrt(max(xsq + wsq - 2*cross, 0))
  // C/D layout: col = lane&15, row = (lane>>4)*4 + reg  [m89/m91]
#pragma unroll
  for (int ti = 0; ti < 4; ++ti) {
    int grow_base = m0 + wr * 64 + ti * 16 + q * 4;
#pragma unroll
    for (int tj = 0; tj < 4; ++tj) {
      int gcol = n0 + wc * 64 + tj * 16 + i;
      if (gcol < NN) {
        float wn = wsq[gcol];
#pragma unroll
        for (int r = 0; r < 4; ++r) {
          int grow = grow_base + r;
          float d2 = xsq[grow] + wn - 2.0f * acc[ti][tj][r];
          out[(size_t)grow * NN + gcol] = sqrtf(fmaxf(d2, 0.f));
        }
      }
    }
  }
}

// ---------------- fallback path (ws too small): round-1 kernels ----------------
#define BK 64
#define LDA 72
__global__ void row_sq_norm(const float* __restrict__ in, float* __restrict__ out,
                            int nrows, int nvalid) {
  int row  = blockIdx.x * 4 + (threadIdx.x >> 6);
  int lane = threadIdx.x & 63;
  if (row >= nrows) return;
  float s = 0.f;
  if (row < nvalid) {
    float4 v = ((const float4*)(in + (size_t)row * DIM))[lane];
    s = v.x * v.x + v.y * v.y + v.z * v.z + v.w * v.w;
  }
  for (int off = 32; off > 0; off >>= 1) s += __shfl_down(s, off, 64);
  if (lane == 0) out[row] = s;
}

__global__ __launch_bounds__(256, 2)
void cdist_gemm_f32(const float* __restrict__ X, const float* __restrict__ W,
                    const float* __restrict__ xsq, const float* __restrict__ wsq,
                    float* __restrict__ out) {
  __shared__ __align__(16) unsigned short As[BM * LDA];
  __shared__ __align__(16) unsigned short Bs[BN * LDA];
  const int tid = threadIdx.x, lane = tid & 63, wave = tid >> 6;
  const int m0 = blockIdx.x * BM, n0 = blockIdx.y * BN;
  const int wr = wave >> 1, wc = wave & 1;
  float4_ acc[4][4] = {};
  const int s_col4 = tid & 15, s_row0 = tid >> 4;
  for (int kc = 0; kc < DIM; kc += BK) {
#pragma unroll
    for (int j = 0; j < 8; ++j) {
      int r = s_row0 + 16 * j;
      float4 v = *(const float4*)(X + (size_t)(m0 + r) * DIM + kc + s_col4 * 4);
      *(ushort4*)&As[r * LDA + s_col4 * 4] =
          make_ushort4(f2bf(v.x), f2bf(v.y), f2bf(v.z), f2bf(v.w));
    }
#pragma unroll
    for (int j = 0; j < 8; ++j) {
      int r = s_row0 + 16 * j, n = n0 + r;
      float4 v = make_float4(0.f, 0.f, 0.f, 0.f);
      if (n < NN) v = *(const float4*)(W + (size_t)n * DIM + kc + s_col4 * 4);
      *(ushort4*)&Bs[r * LDA + s_col4 * 4] =
          make_ushort4(f2bf(v.x), f2bf(v.y), f2bf(v.z), f2bf(v.w));
    }
    __syncthreads();
    const int q = lane >> 4, i = lane & 15;
#pragma unroll
    for (int ks = 0; ks < BK; ks += 32) {
      short8 a[4], b[4];
#pragma unroll
      for (int t = 0; t < 4; ++t) {
        a[t] = *(const short8*)&As[(wr * 64 + t * 16 + i) * LDA + ks + q * 8];
        b[t] = *(const short8*)&Bs[(wc * 64 + t * 16 + i) * LDA + ks + q * 8];
      }
#pragma unroll
      for (int ti = 0; ti < 4; ++ti)
#pragma unroll
        for (int tj = 0; tj < 4; ++tj)
          acc[ti][tj] = __builtin_amdgcn_mfma_f32_16x16x32_bf16(
              a[ti], b[tj], acc[ti][tj], 0, 0, 0);
    }
    __syncthreads();
  }
  const int q = lane >> 4, i = lane & 15;
#pragma unroll
  for (int ti = 0; ti < 4; ++ti) {
    int grow_base = m0 + wr * 64 + ti * 16 + q * 4;
#pragma unroll
    for (int tj = 0; tj < 4; ++tj) {
      int gcol = n0 + wc * 64 + tj * 16 + i;
      if (gcol < NN) {
        float wn = wsq[gcol];
#pragma unroll
        for (int r = 0; r < 4; ++r) {
          int grow = grow_base + r;
          float d2 = xsq[grow] + wn - 2.0f * acc[ti][tj][r];
          out[(size_t)grow * NN + gcol] = sqrtf(fmaxf(d2, 0.f));
        }
      }
    }
  }
}

extern "C" void kernel_launch(void* const* d_in, const int* in_sizes, int n_in,
                              void* d_out, int out_size, void* d_ws, size_t ws_size,
                              hipStream_t stream) {
  const float* x = (const float*)d_in[0];
  const float* w = (const float*)d_in[1];

  const size_t xb_elems = (size_t)BATCH * DIM;          // bf16
  const size_t wb_elems = (size_t)NPAD * DIM;           // bf16
  const size_t need = xb_elems * 2 + wb_elems * 2 + (size_t)BATCH * 4 + (size_t)NPAD * 4;

  if (ws_size >= need) {
    unsigned short* Xb = (unsigned short*)d_ws;
    unsigned short* Wb = Xb + xb_elems;
    float* xsq = (float*)(Wb + wb_elems);
    float* wsq = xsq + BATCH;

    prep_rows<<<BATCH / 4, 256, 0, stream>>>(x, Xb, xsq, BATCH, BATCH);
    prep_rows<<<NPAD / 4, 256, 0, stream>>>(w, Wb, wsq, NPAD, NN);

    dim3 grid(BATCH / BM, NPAD / BN);
    cdist_gemm_direct<<<grid, 256, 0, stream>>>(Xb, Wb, xsq, wsq, (float*)d_out);
  } else {
    float* xsq = (float*)d_ws;
    float* wsq = xsq + BATCH;
    row_sq_norm<<<BATCH / 4, 256, 0, stream>>>(x, xsq, BATCH, BATCH);
    row_sq_norm<<<NPAD / 4, 256, 0, stream>>>(w, wsq, NPAD, NN);
    dim3 grid(BATCH / BM, NPAD / BN);
    cdist_gemm_f32<<<grid, 256, 0, stream>>>(x, w, xsq, wsq, (float*)d_out);
  }
}